// Round 10
// baseline (4422.273 us; speedup 1.0000x reference)
//
#include <hip/hip_runtime.h>
#include <stdio.h>
#include <stdint.h>

typedef __attribute__((ext_vector_type(8))) short short8;     // 8 x bf16 bits (4 VGPRs)
typedef __attribute__((ext_vector_type(4))) float f32x4;      // MFMA accum
typedef __attribute__((ext_vector_type(4))) unsigned short ushort4v;

__device__ __forceinline__ unsigned short f2bf(float f) {
  unsigned int u = __builtin_bit_cast(unsigned int, f);
  u = u + 0x7FFFu + ((u >> 16) & 1u);   // RNE
  return (unsigned short)(u >> 16);
}
__device__ __forceinline__ float bf2f(unsigned short h) {
  unsigned int u = ((unsigned int)h) << 16;
  return __builtin_bit_cast(float, u);
}

// async global->LDS, 16B per lane; LDS dest = wave-uniform base + lane*16
__device__ __forceinline__ void gl_lds16(const unsigned short* g, unsigned short* l) {
  __builtin_amdgcn_global_load_lds(
      (const __attribute__((address_space(1))) unsigned int*)(const void*)g,
      (__attribute__((address_space(3))) unsigned int*)(void*)l, 16, 0, 0);
}

// -------- tiled transpose+cast (+zero pad): out[n][k] = f2bf(in[k][n]); coalesced both sides --------
__global__ void k_transpose_cast_t(const float* __restrict__ in, unsigned short* __restrict__ out,
                                   int Nin, int Kin, int ldo) {
  __shared__ float lds[64][65];
  int k0 = blockIdx.x * 64, n0 = blockIdx.y * 64;
  int t = threadIdx.x, tc = t & 15, tr = t >> 4;
  #pragma unroll
  for (int rr = 0; rr < 4; ++rr) {
    int kl = tr + rr * 16, k = k0 + kl;
    #pragma unroll
    for (int j = 0; j < 4; ++j) {
      int nl = tc * 4 + j, n = n0 + nl;
      lds[kl][nl] = (k < Kin && n < Nin) ? in[(size_t)k * Nin + n] : 0.f;
    }
  }
  __syncthreads();
  #pragma unroll
  for (int rr = 0; rr < 4; ++rr) {
    int nl = tr + rr * 16, n = n0 + nl;
    int kb = k0 + tc * 4;
    if (kb + 3 < ldo) {
      ushort4v o;
      o.x = f2bf(lds[tc * 4 + 0][nl]);
      o.y = f2bf(lds[tc * 4 + 1][nl]);
      o.z = f2bf(lds[tc * 4 + 2][nl]);
      o.w = f2bf(lds[tc * 4 + 3][nl]);
      *(ushort4v*)&out[(size_t)n * ldo + kb] = o;
    } else {
      for (int j = 0; j < 4; ++j)
        if (kb + j < ldo) out[(size_t)n * ldo + kb + j] = f2bf(lds[tc * 4 + j][nl]);
    }
  }
}

// ---------------- att layer 1: h = relu(t[b]*W2a[j] + b2a[j]) -> bf16 [2048x1024] ----------------
__global__ void k_att_l1(const float* __restrict__ tar, const float* __restrict__ W2a,
                         const float* __restrict__ b2a, unsigned short* __restrict__ out) {
  int id = blockIdx.x * 256 + threadIdx.x;   // 2048*1024
  int b = id >> 10, j = id & 1023;
  out[id] = f2bf(fmaxf(tar[b] * W2a[j] + b2a[j], 0.f));
}

// ---------------- v2s cast to bf16, K padded 312->320 ----------------
__global__ void k_v2s_cast(const float* __restrict__ v2s, unsigned short* __restrict__ out) {
  int id = blockIdx.x * 256 + threadIdx.x;   // 2048*320
  int r = id / 320, c = id - r * 320;
  out[id] = (c < 312) ? f2bf(v2s[(size_t)r * 312 + c]) : (unsigned short)0;
}

// ====== 128x128 bf16 GEMM, double-buffered (R8-proven) — used for att-MLP / layer-1 ======
__device__ __forceinline__ int lds_off(int row, int g) {
  int slot = (g + (row >> 1)) & 3;
  return row * 32 + slot * 8;                 // ushort units, ld=32
}

template<bool RELU, bool OUTBF16>
__global__ __launch_bounds__(256)
void k_gemm_bt(const unsigned short* __restrict__ A, const unsigned short* __restrict__ B,
               const float* __restrict__ bias, int bias_n, int nNt, int N_store, int K,
               void* __restrict__ outp, int ldo, int remap) {
  __shared__ __align__(16) unsigned short As[2][4096];
  __shared__ __align__(16) unsigned short Bs[2][4096];
  int d = blockIdx.x, nwg = gridDim.x;
  int L = d;
  if (remap) { int q = nwg >> 3; L = (d & 7) * q + (d >> 3); }
  int mt = L / nNt, nt = L - mt * nNt;
  size_t m0 = (size_t)mt * 128, n0 = (size_t)nt * 128;
  int tid = threadIdx.x, lane = tid & 63;
  int w = tid >> 6, wr = w >> 1, wc = w & 1;
  int sr = tid >> 2;
  int gch = ((tid & 3) - (tid >> 3)) & 3;
  const unsigned short* pA0 = A + (m0 + sr) * K + gch * 8;
  const unsigned short* pA1 = pA0 + (size_t)64 * K;
  const unsigned short* pB0 = B + (n0 + sr) * K + gch * 8;
  const unsigned short* pB1 = pB0 + (size_t)64 * K;
  int sd = (tid & ~63) * 8;

  int kg = lane >> 4, l15 = lane & 15;
  int aoff = lds_off(wr * 64 + l15, kg);
  int boff = lds_off(wc * 64 + l15, kg);

  f32x4 acc[4][4];
  #pragma unroll
  for (int i = 0; i < 4; ++i)
    #pragma unroll
    for (int j = 0; j < 4; ++j) acc[i][j] = (f32x4)(0.f);

  const int NT = K >> 5;
#define STAGE(t_, b_) do { int k0_ = (t_) * 32;                       \
    gl_lds16(pA0 + k0_, &As[b_][sd]);                                 \
    gl_lds16(pA1 + k0_, &As[b_][2048 + sd]);                          \
    gl_lds16(pB0 + k0_, &Bs[b_][sd]);                                 \
    gl_lds16(pB1 + k0_, &Bs[b_][2048 + sd]);                          \
  } while (0)

  STAGE(0, 0);
  for (int t = 0; t < NT; ++t) {
    int b = t & 1;
    __syncthreads();
    if (t + 1 < NT) STAGE(t + 1, b ^ 1);
    short8 af[4], bfr[4];
    #pragma unroll
    for (int mi = 0; mi < 4; ++mi) af[mi] = *(const short8*)&As[b][aoff + mi * 512];
    #pragma unroll
    for (int ni = 0; ni < 4; ++ni) bfr[ni] = *(const short8*)&Bs[b][boff + ni * 512];
    #pragma unroll
    for (int mi = 0; mi < 4; ++mi)
      #pragma unroll
      for (int ni = 0; ni < 4; ++ni)
        acc[mi][ni] = __builtin_amdgcn_mfma_f32_16x16x32_bf16(af[mi], bfr[ni], acc[mi][ni], 0, 0, 0);
  }
#undef STAGE

  #pragma unroll
  for (int ni = 0; ni < 4; ++ni) {
    int colg = (int)n0 + wc * 64 + ni * 16 + l15;
    if (colg < N_store) {
      float bs = bias ? (colg < bias_n ? bias[colg] : 0.f) : 0.f;
      #pragma unroll
      for (int mi = 0; mi < 4; ++mi) {
        #pragma unroll
        for (int r2 = 0; r2 < 4; ++r2) {
          size_t rowg = m0 + wr * 64 + mi * 16 + kg * 4 + r2;
          float v = acc[mi][ni][r2] + bs;
          if (RELU) v = fmaxf(v, 0.f);
          if (OUTBF16) ((unsigned short*)outp)[rowg * ldo + colg] = f2bf(v);
          else         ((float*)outp)[rowg * ldo + colg] = v;
        }
      }
    }
  }
}

// ============ FUSED layer2+layer3 fat block ============
// Block = 256 m-rows x ALL N=2048 (nt-loop of 16 x 128). 512 thr = 8 waves (4Mq x 2Nq).
// Per nt: dbuf K-loop (K=1024, BK=32) -> acc[4][4] = C[nt] quadrants; W1c-slice staged into
// LDS during K-loop tail (drained by the loop's own __syncthreads); Ct = bf16 relu(C+b1b)
// written to LDS (overlaying staging bufs, 2 m-halves); mini-GEMM Pacc += Ct @ Wc accumulates
// layer-3 in REGISTERS across nt (split-K without atomics -> deterministic).
// Epilogue: P = relu(Pacc + b1c), f32, written once. H2 never exists.
// LDS 80KB: Abuf 2x8192ush @0 | Bbuf 2x4096ush @16384 | Wc 16384ush @24576; Ct overlays @0.
// Ct/Wc swizzle: chunk c (8 ush) of row r at slot (c+r)&15 -> reads are 2-way conflicts (free).
#define WCOFF 24576
__global__ __launch_bounds__(512)
void k_l23_fat(const unsigned short* __restrict__ H1, const unsigned short* __restrict__ W1bT,
               const unsigned short* __restrict__ W1cT, const float* __restrict__ b1b,
               const float* __restrict__ b1c, float* __restrict__ P, int rbase) {
  __shared__ __align__(16) unsigned short sm[40960];   // 80 KiB
  int tid = threadIdx.x, lane = tid & 63, w = tid >> 6;
  int wr = w >> 1, wc = w & 1;                 // wr: 64-row m-quad (0..3), wc: 64-col quad (0..1)
  int kg = lane >> 4, l15 = lane & 15;
  size_t m0 = (size_t)blockIdx.x * 256;        // local to chunk

  int srow = tid >> 2;                         // 0..127
  int gch = ((tid & 3) - (tid >> 3)) & 3;      // pre-swizzled global chunk (rule #21)
  const unsigned short* pA0 = H1 + (m0 + srow) * 1024 + gch * 8;
  const unsigned short* pA1 = pA0 + (size_t)128 * 1024;
  int sd = (tid & ~63) * 8;                    // wave-uniform dest (512 ush per wave)

  int aoff = lds_off(wr * 64 + l15, kg);       // A rows 256, ld=32
  int boff = lds_off(wc * 64 + l15, kg);       // B rows 128
  int ctrow[4], wcrow[4];
  #pragma unroll
  for (int i = 0; i < 4; ++i) {
    ctrow[i] = (wr & 1) * 64 + i * 16 + l15;   // mini A rows (within 128-row half)
    wcrow[i] = wc * 64 + i * 16 + l15;         // mini B rows (p)
  }

  f32x4 Pacc[4][4];
  #pragma unroll
  for (int i = 0; i < 4; ++i)
    #pragma unroll
    for (int j = 0; j < 4; ++j) Pacc[i][j] = (f32x4)(0.f);

  for (int nt = 0; nt < 16; ++nt) {
    const unsigned short* pB0 = W1bT + (size_t)(nt * 128 + srow) * 1024 + gch * 8;
    float bb[4];
    #pragma unroll
    for (int ni = 0; ni < 4; ++ni) bb[ni] = b1b[nt * 128 + wc * 64 + ni * 16 + l15];

    f32x4 acc[4][4];
    #pragma unroll
    for (int i = 0; i < 4; ++i)
      #pragma unroll
      for (int j = 0; j < 4; ++j) acc[i][j] = (f32x4)(0.f);

#define FSTAGE(t_, b_) do { int k0_ = (t_) * 32;                        \
    gl_lds16(pA0 + k0_, &sm[(b_) * 8192 + sd]);                         \
    gl_lds16(pA1 + k0_, &sm[(b_) * 8192 + 4096 + sd]);                  \
    gl_lds16(pB0 + k0_, &sm[16384 + (b_) * 4096 + sd]);                 \
  } while (0)

    FSTAGE(0, 0);
    for (int t = 0; t < 32; ++t) {
      int b = t & 1;
      __syncthreads();                         // drains stage(t) (1 tile of slack) + Wc calls
      if (t + 1 < 32) FSTAGE(t + 1, b ^ 1);
      if (t >= 28) {                           // stage W1c-slice (32 calls over 4 tail steps)
        int p0 = w * 16 + (t & 3) * 4;
        int prow = p0 + (lane >> 4);
        const unsigned short* src = W1cT + (size_t)prow * 2048 + nt * 128
                                    + (((lane & 15) - prow) & 15) * 8;
        gl_lds16(src, &sm[WCOFF + p0 * 128]);
      }
      short8 af[4], bfr[4];
      #pragma unroll
      for (int mi = 0; mi < 4; ++mi) af[mi] = *(const short8*)&sm[b * 8192 + aoff + mi * 512];
      #pragma unroll
      for (int ni = 0; ni < 4; ++ni) bfr[ni] = *(const short8*)&sm[16384 + b * 4096 + boff + ni * 512];
      #pragma unroll
      for (int mi = 0; mi < 4; ++mi)
        #pragma unroll
        for (int ni = 0; ni < 4; ++ni)
          acc[mi][ni] = __builtin_amdgcn_mfma_f32_16x16x32_bf16(af[mi], bfr[ni], acc[mi][ni], 0, 0, 0);
    }
#undef FSTAGE
    __syncthreads();                           // all frag reads + last Wc stages complete

    // ---- layer-3 mini in two 128-row halves (Ct overlays staging bufs: 128x128 bf16) ----
    #pragma unroll
    for (int h = 0; h < 2; ++h) {
      if ((wr >> 1) == h) {                    // write Ct = bf16(relu(acc + b1b))
        #pragma unroll
        for (int mi = 0; mi < 4; ++mi)
          #pragma unroll
          for (int ni = 0; ni < 4; ++ni)
            #pragma unroll
            for (int r2 = 0; r2 < 4; ++r2) {
              float v = fmaxf(acc[mi][ni][r2] + bb[ni], 0.f);
              float vp = __shfl_xor(v, 1);     // partner lane's adjacent-n value
              if (!(l15 & 1)) {
                unsigned int pk = (unsigned int)f2bf(v) | ((unsigned int)f2bf(vp) << 16);
                int m_l = (wr & 1) * 64 + mi * 16 + kg * 4 + r2;
                int n_l = wc * 64 + ni * 16 + (l15 & ~1);
                int idx = m_l * 128 + ((((n_l >> 3) + m_l) & 15) << 3) + (n_l & 7);
                *(unsigned int*)&sm[idx] = pk;
              }
            }
      }
      __syncthreads();
      if ((wr >> 1) == h) {                    // Pacc += Ct @ Wc  (K = 128 = this nt's n)
        #pragma unroll
        for (int ks = 0; ks < 4; ++ks) {
          short8 ca[4], wb[4];
          #pragma unroll
          for (int mi = 0; mi < 4; ++mi)
            ca[mi] = *(const short8*)&sm[ctrow[mi] * 128 + (((ks * 4 + kg + ctrow[mi]) & 15) << 3)];
          #pragma unroll
          for (int ni = 0; ni < 4; ++ni)
            wb[ni] = *(const short8*)&sm[WCOFF + wcrow[ni] * 128 + (((ks * 4 + kg + wcrow[ni]) & 15) << 3)];
          #pragma unroll
          for (int mi = 0; mi < 4; ++mi)
            #pragma unroll
            for (int ni = 0; ni < 4; ++ni)
              Pacc[mi][ni] = __builtin_amdgcn_mfma_f32_16x16x32_bf16(ca[mi], wb[ni], Pacc[mi][ni], 0, 0, 0);
        }
      }
      __syncthreads();                         // Ct reads done before next nt's FSTAGE(0)
    }
  }

  // ---- epilogue: P = relu(Pacc + b1c), f32, written once (no atomics) ----
  #pragma unroll
  for (int ni = 0; ni < 4; ++ni) {
    int colp = wc * 64 + ni * 16 + l15;
    float bc = b1c[colp];
    #pragma unroll
    for (int mi = 0; mi < 4; ++mi) {
      #pragma unroll
      for (int r2 = 0; r2 < 4; ++r2) {
        size_t rowg = (size_t)rbase + m0 + wr * 64 + mi * 16 + kg * 4 + r2;
        P[rowg * 128 + colp] = fmaxf(Pacc[mi][ni][r2] + bc, 0.f);
      }
    }
  }
}
#undef WCOFF

// ------- H1c[r_local] = relu(V1[src] + A1p[arow]) -> bf16  (b1a pre-folded into A1p) -------
__global__ void k_build_h1(const float* __restrict__ V1, const float* __restrict__ A1p,
                           const int* __restrict__ idx, unsigned short* __restrict__ H1c,
                           int rbase) {
  int row = rbase + blockIdx.x;                // global row 0..133119
  int src, arow;
  if (row < 2048) { src = row; arow = row; }   // rows 0..2047 = query
  else {
    int g = row - 2048; arow = g >> 6;
    int s = idx[g];
    src = s < 0 ? 0 : (s > 2047 ? 2047 : s);
  }
  int j = threadIdx.x * 4;
  float4 v = *(const float4*)(V1 + (size_t)src * 1024 + j);
  float4 a = *(const float4*)(A1p + (size_t)arow * 1024 + j);
  ushort4v o;
  o.x = f2bf(fmaxf(v.x + a.x, 0.f));
  o.y = f2bf(fmaxf(v.y + a.y, 0.f));
  o.z = f2bf(fmaxf(v.z + a.z, 0.f));
  o.w = f2bf(fmaxf(v.w + a.w, 0.f));
  *(ushort4v*)(H1c + (size_t)blockIdx.x * 1024 + j) = o;
}

// ---------------- logits[b,k] = dot(P[b], P[2048 + b*64 + k]) / T  (P is f32) ----------------
__global__ void k_dot(const float* __restrict__ P, float* __restrict__ out) {
  __shared__ float q[128];
  int b = blockIdx.x, t = threadIdx.x;
  if (t < 128) q[t] = P[(size_t)b * 128 + t];
  __syncthreads();
  int k = t >> 2, part = t & 3;
  const float* row = P + (size_t)(2048 + b * 64 + k) * 128 + part * 32;
  const float* qp = q + part * 32;
  float s = 0.f;
  #pragma unroll
  for (int j = 0; j < 32; j += 4) {
    float4 pv = *(const float4*)(row + j);
    s += pv.x * qp[j] + pv.y * qp[j + 1] + pv.z * qp[j + 2] + pv.w * qp[j + 3];
  }
  s += __shfl_xor(s, 1);
  s += __shfl_xor(s, 2);
  if (part == 0) out[(size_t)b * 64 + k] = s * (float)(1.0 / 0.12);
}

extern "C" void kernel_launch(void* const* d_in, const int* in_sizes, int n_in,
                              void* d_out, int out_size, void* d_ws, size_t ws_size,
                              hipStream_t stream) {
  const float* v2s = (const float*)d_in[0];
  const float* tar = (const float*)d_in[1];
  const int*   sidx = (const int*)d_in[2];
  const float* W2a = (const float*)d_in[3];
  const float* b2a = (const float*)d_in[4];
  const float* W2b = (const float*)d_in[5];
  const float* b2b = (const float*)d_in[6];
  const float* W2c = (const float*)d_in[7];
  const float* b2c = (const float*)d_in[8];
  const float* W1a = (const float*)d_in[9];
  const float* b1a = (const float*)d_in[10];
  const float* W1b = (const float*)d_in[11];
  const float* b1b = (const float*)d_in[12];
  const float* W1c = (const float*)d_in[13];
  const float* b1c = (const float*)d_in[14];
  float* out = (float*)d_out;

  char* ws = (char*)d_ws;
  size_t off = 0;
  auto alloc = [&](size_t bytes) -> char* {
    char* p = ws + off; off += (bytes + 255) & ~(size_t)255; return p;
  };
  // persistent
  unsigned short* W1bT = (unsigned short*)alloc(2048ull * 1024 * 2);  // [2048][1024]
  unsigned short* W1cT = (unsigned short*)alloc(128ull * 2048 * 2);   // [128][2048]
  float*          V1   = (float*)alloc(2048ull * 1024 * 4);           // v2s @ W1a
  float*          A1p  = (float*)alloc(2048ull * 1024 * 4);           // att @ W1a + b1a
  float*          P    = (float*)alloc(133120ull * 128 * 4);          // f32 projections (relu'd)
  // overlay
  size_t O = off;
  off = O;
  unsigned short* W1aT = (unsigned short*)alloc(1024ull * 320 * 2);   // [1024][320]  (K-pad)
  unsigned short* v2sb = (unsigned short*)alloc(2048ull * 320 * 2);
  unsigned short* attb = (unsigned short*)alloc(2048ull * 320 * 2);
  unsigned short* W2bT = (unsigned short*)alloc(2048ull * 1024 * 2);
  unsigned short* W2cT = (unsigned short*)alloc(384ull * 2048 * 2);   // [384][2048]  (N-pad)
  unsigned short* h_a  = (unsigned short*)alloc(2048ull * 1024 * 2);
  unsigned short* h2a  = (unsigned short*)alloc(2048ull * 2048 * 2);
  size_t early_end = off;

  // ---- chunk plans in 256-row m-tiles, sum = 520. Only H1c lives in the late overlay now.
  static const int plans[4][8] = {{520,0,0,0,0,0,0,0},
                                  {260,260,0,0,0,0,0,0},
                                  {130,130,130,130,0,0,0,0},
                                  {65,65,65,65,65,65,65,65}};
  int sel = -1, maxmt = 0;
  for (int p = 0; p < 4 && sel < 0; ++p) {
    int mx = 0;
    for (int i = 0; i < 8; ++i) if (plans[p][i] > mx) mx = plans[p][i];
    size_t rows = (size_t)mx * 256;
    size_t late = O + ((rows * 1024 * 2 + 255) & ~(size_t)255);
    size_t need = late > early_end ? late : early_end;
    if (need <= ws_size) { sel = p; maxmt = mx; }
  }
  fprintf(stderr, "[kernel_launch] ws_size=%zu sel=%d\n", ws_size, sel);
  if (sel < 0) {
    hipMemsetAsync(d_out, 0, (size_t)out_size * 4, stream);
    return;
  }
  off = O;
  unsigned short* H1c = (unsigned short*)alloc((size_t)maxmt * 256 * 1024 * 2);

  dim3 blk(256);
  // weight prep (tiled coalesced transpose)
  k_transpose_cast_t<<<dim3(16, 32), blk, 0, stream>>>(W2b, W2bT, 2048, 1024, 1024);
  k_transpose_cast_t<<<dim3(32, 6),  blk, 0, stream>>>(W2c, W2cT, 312, 2048, 2048);
  k_transpose_cast_t<<<dim3(5, 16),  blk, 0, stream>>>(W1a, W1aT, 1024, 312, 320);
  k_transpose_cast_t<<<dim3(16, 32), blk, 0, stream>>>(W1b, W1bT, 2048, 1024, 1024);
  k_transpose_cast_t<<<dim3(32, 2),  blk, 0, stream>>>(W1c, W1cT, 128, 2048, 2048);
  k_att_l1<<<8192, blk, 0, stream>>>(tar, W2a, b2a, h_a);
  k_v2s_cast<<<2560, blk, 0, stream>>>(v2s, v2sb);
  // att MLP
  k_gemm_bt<true,  true ><<<256, blk, 0, stream>>>(h_a,  W2bT, b2b, 2048, 16, 2048, 1024, h2a,  2048, 1);
  k_gemm_bt<true,  true ><<<48,  blk, 0, stream>>>(h2a,  W2cT, b2c, 312,  3,  320,  2048, attb, 320,  1);
  // layer-1 factored
  k_gemm_bt<false, false><<<128, blk, 0, stream>>>(v2sb, W1aT, nullptr, 0,  8, 1024, 320, V1,  1024, 1);
  k_gemm_bt<false, false><<<128, blk, 0, stream>>>(attb, W1aT, b1a, 1024,  8, 1024, 320, A1p, 1024, 1);
  // chunked: build H1 -> fused layer2+layer3 (P written directly, H2 never materialized)
  int rbase = 0;
  for (int i = 0; i < 8 && plans[sel][i]; ++i) {
    int mtc = plans[sel][i];
    int R = mtc * 256;
    k_build_h1<<<R, blk, 0, stream>>>(V1, A1p, sidx, H1c, rbase);
    k_l23_fat<<<mtc, dim3(512), 0, stream>>>(H1c, W1bT, W1cT, b1b, b1c, P, rbase);
    rbase += R;
  }
  // logits
  k_dot<<<2048, blk, 0, stream>>>(P, out);
}

// Round 12
// 1066.442 us; speedup vs baseline: 4.1468x; 4.1468x over previous
//
#include <hip/hip_runtime.h>
#include <stdio.h>
#include <stdint.h>

typedef __attribute__((ext_vector_type(8))) short short8;     // 8 x bf16 bits (4 VGPRs)
typedef __attribute__((ext_vector_type(4))) float f32x4;      // MFMA accum
typedef __attribute__((ext_vector_type(4))) unsigned short ushort4v;

__device__ __forceinline__ unsigned short f2bf(float f) {
  unsigned int u = __builtin_bit_cast(unsigned int, f);
  u = u + 0x7FFFu + ((u >> 16) & 1u);   // RNE
  return (unsigned short)(u >> 16);
}
__device__ __forceinline__ float bf2f(unsigned short h) {
  unsigned int u = ((unsigned int)h) << 16;
  return __builtin_bit_cast(float, u);
}

// async global->LDS, 16B per lane; LDS dest = wave-uniform base + lane*16
__device__ __forceinline__ void gl_lds16(const void* g, void* l) {
  __builtin_amdgcn_global_load_lds(
      (const __attribute__((address_space(1))) unsigned int*)g,
      (__attribute__((address_space(3))) unsigned int*)l, 16, 0, 0);
}

// -------- tiled transpose+cast bf16 (+zero pad): out[n][k] = f2bf(in[k][n]) --------
__global__ void k_transpose_cast_t(const float* __restrict__ in, unsigned short* __restrict__ out,
                                   int Nin, int Kin, int ldo) {
  __shared__ float lds[64][65];
  int k0 = blockIdx.x * 64, n0 = blockIdx.y * 64;
  int t = threadIdx.x, tc = t & 15, tr = t >> 4;
  #pragma unroll
  for (int rr = 0; rr < 4; ++rr) {
    int kl = tr + rr * 16, k = k0 + kl;
    #pragma unroll
    for (int j = 0; j < 4; ++j) {
      int nl = tc * 4 + j, n = n0 + nl;
      lds[kl][nl] = (k < Kin && n < Nin) ? in[(size_t)k * Nin + n] : 0.f;
    }
  }
  __syncthreads();
  #pragma unroll
  for (int rr = 0; rr < 4; ++rr) {
    int nl = tr + rr * 16, n = n0 + nl;
    int kb = k0 + tc * 4;
    if (kb + 3 < ldo) {
      ushort4v o;
      o.x = f2bf(lds[tc * 4 + 0][nl]);
      o.y = f2bf(lds[tc * 4 + 1][nl]);
      o.z = f2bf(lds[tc * 4 + 2][nl]);
      o.w = f2bf(lds[tc * 4 + 3][nl]);
      *(ushort4v*)&out[(size_t)n * ldo + kb] = o;
    } else {
      for (int j = 0; j < 4; ++j)
        if (kb + j < ldo) out[(size_t)n * ldo + kb + j] = f2bf(lds[tc * 4 + j][nl]);
    }
  }
}

// ---------------- att layer 1: h = relu(t[b]*W2a[j] + b2a[j]) -> bf16 [2048x1024] ----------------
__global__ void k_att_l1(const float* __restrict__ tar, const float* __restrict__ W2a,
                         const float* __restrict__ b2a, unsigned short* __restrict__ out) {
  int id = blockIdx.x * 256 + threadIdx.x;   // 2048*1024
  int b = id >> 10, j = id & 1023;
  out[id] = f2bf(fmaxf(tar[b] * W2a[j] + b2a[j], 0.f));
}

// ---------------- v2s cast to bf16, K padded 312->320 ----------------
__global__ void k_v2s_cast(const float* __restrict__ v2s, unsigned short* __restrict__ out) {
  int id = blockIdx.x * 256 + threadIdx.x;   // 2048*320
  int r = id / 320, c = id - r * 320;
  out[id] = (c < 312) ? f2bf(v2s[(size_t)r * 312 + c]) : (unsigned short)0;
}

// LDS slot helper (BK=32 kernels): slot of 4 per row
__device__ __forceinline__ int lds_off(int row, int g) {
  int slot = (g + (row >> 1)) & 3;
  return row * 32 + slot * 8;                 // ushort units, row = 64B
}

// ====== 128x128 bf16 GEMM, BK=32 double-buffered (R8-proven) — att-MLP / layer-1 / layer-3 ======
template<bool RELU, bool OUTBF16>
__global__ __launch_bounds__(256)
void k_gemm_bt(const unsigned short* __restrict__ A, const unsigned short* __restrict__ B,
               const float* __restrict__ bias, int bias_n, int nNt, int N_store, int K,
               void* __restrict__ outp, int ldo, int remap) {
  __shared__ __align__(16) unsigned short As[2][4096];
  __shared__ __align__(16) unsigned short Bs[2][4096];
  int d = blockIdx.x, nwg = gridDim.x;
  int L = d;
  if (remap) { int q = nwg >> 3; L = (d & 7) * q + (d >> 3); }
  int mt = L / nNt, nt = L - mt * nNt;
  size_t m0 = (size_t)mt * 128, n0 = (size_t)nt * 128;
  int tid = threadIdx.x, lane = tid & 63;
  int w = tid >> 6, wr = w >> 1, wc = w & 1;
  int sr = tid >> 2;
  int gch = ((tid & 3) - (tid >> 3)) & 3;
  const unsigned short* pA0 = A + (m0 + sr) * K + gch * 8;
  const unsigned short* pA1 = pA0 + (size_t)64 * K;
  const unsigned short* pB0 = B + (n0 + sr) * K + gch * 8;
  const unsigned short* pB1 = pB0 + (size_t)64 * K;
  int sd = (tid & ~63) * 8;

  int kg = lane >> 4, l15 = lane & 15;
  int aoff = lds_off(wr * 64 + l15, kg);
  int boff = lds_off(wc * 64 + l15, kg);

  f32x4 acc[4][4];
  #pragma unroll
  for (int i = 0; i < 4; ++i)
    #pragma unroll
    for (int j = 0; j < 4; ++j) acc[i][j] = (f32x4)(0.f);

  const int NT = K >> 5;
#define STAGE(t_, b_) do { int k0_ = (t_) * 32;                       \
    gl_lds16(pA0 + k0_, &As[b_][sd]);                                 \
    gl_lds16(pA1 + k0_, &As[b_][2048 + sd]);                          \
    gl_lds16(pB0 + k0_, &Bs[b_][sd]);                                 \
    gl_lds16(pB1 + k0_, &Bs[b_][2048 + sd]);                          \
  } while (0)

  STAGE(0, 0);
  for (int t = 0; t < NT; ++t) {
    int b = t & 1;
    __syncthreads();                          // implicit vmcnt(0): stage(t) landed
    if (t + 1 < NT) STAGE(t + 1, b ^ 1);      // issue early -> full tile of slack
    short8 af[4], bfr[4];
    #pragma unroll
    for (int mi = 0; mi < 4; ++mi) af[mi] = *(const short8*)&As[b][aoff + mi * 512];
    #pragma unroll
    for (int ni = 0; ni < 4; ++ni) bfr[ni] = *(const short8*)&Bs[b][boff + ni * 512];
    #pragma unroll
    for (int mi = 0; mi < 4; ++mi)
      #pragma unroll
      for (int ni = 0; ni < 4; ++ni)
        acc[mi][ni] = __builtin_amdgcn_mfma_f32_16x16x32_bf16(af[mi], bfr[ni], acc[mi][ni], 0, 0, 0);
  }
#undef STAGE

  #pragma unroll
  for (int ni = 0; ni < 4; ++ni) {
    int colg = (int)n0 + wc * 64 + ni * 16 + l15;
    if (colg < N_store) {
      float bs = bias ? (colg < bias_n ? bias[colg] : 0.f) : 0.f;
      #pragma unroll
      for (int mi = 0; mi < 4; ++mi) {
        #pragma unroll
        for (int r2 = 0; r2 < 4; ++r2) {
          size_t rowg = m0 + wr * 64 + mi * 16 + kg * 4 + r2;
          float v = acc[mi][ni][r2] + bs;
          if (RELU) v = fmaxf(v, 0.f);
          if (OUTBF16) ((unsigned short*)outp)[rowg * ldo + colg] = f2bf(v);
          else         ((float*)outp)[rowg * ldo + colg] = v;
        }
      }
    }
  }
}

// ====== 128x128 bf16 GEMM, BK=64 (layer-2): halves barrier-interval count ======
// Tests fixed-per-interval-overhead hypothesis: 16 intervals x 32 MFMA vs 32 x 16.
// LDS 64KB (2 blocks/CU). 8-slot swizzle: slot s of row r holds k-chunk (s-(r>>1))&7;
// inverse applied on per-lane global src (rule #21). Frag reads 2-way max = free (derived:
// 16 lanes span 16 rows -> 8 slot values x 2 -> 2 lanes/bank-quad). C = relu(acc+bias) bf16.
__global__ __launch_bounds__(256)
void k_gemm64(const unsigned short* __restrict__ A, const unsigned short* __restrict__ B,
              const float* __restrict__ bias, int nNt, int K,
              unsigned short* __restrict__ outp, int ldo) {
  __shared__ __align__(16) unsigned short As[2][8192];   // [buf][128 rows x 64 ush]
  __shared__ __align__(16) unsigned short Bs[2][8192];
  int d = blockIdx.x, nwg = gridDim.x;
  int q = nwg >> 3;                            // nwg % 8 == 0 at all call sites
  int L = (d & 7) * q + (d >> 3);
  int mt = L / nNt, nt = L - mt * nNt;
  size_t m0 = (size_t)mt * 128, n0 = (size_t)nt * 128;
  int tid = threadIdx.x, lane = tid & 63;
  int w = tid >> 6, wr = w >> 1, wc = w & 1;

  // staging: wave w call j covers rows (w*4+j)*8..+7; lane l -> row +(l>>3), slot l&7
  int l3 = lane >> 3, s8 = lane & 7;
  const unsigned short* pA[4];
  const unsigned short* pB[4];
  int sdst[4];
  #pragma unroll
  for (int j = 0; j < 4; ++j) {
    int row = w * 32 + j * 8 + l3;
    int g = (s8 - (row >> 1)) & 7;             // inverse swizzle on global chunk
    pA[j] = A + (m0 + row) * K + g * 8;
    pB[j] = B + (n0 + row) * K + g * 8;
    sdst[j] = (w * 4 + j) * 512;               // ush; wave-uniform, HW adds lane*16B
  }

  int kg = lane >> 4, l15 = lane & 15;
  int ra = wr * 64 + l15, rb = wc * 64 + l15;
  int aoffs[2], boffs[2];
  #pragma unroll
  for (int ks = 0; ks < 2; ++ks) {             // k-slice ks: chunk c = ks*4+kg
    aoffs[ks] = ra * 64 + ((ks * 4 + kg + (ra >> 1)) & 7) * 8;
    boffs[ks] = rb * 64 + ((ks * 4 + kg + (rb >> 1)) & 7) * 8;
  }

  f32x4 acc[4][4];
  #pragma unroll
  for (int i = 0; i < 4; ++i)
    #pragma unroll
    for (int j = 0; j < 4; ++j) acc[i][j] = (f32x4)(0.f);

  const int NT = K >> 6;                       // K % 64 == 0
#define STAGE64(t_, b_) do { int k0_ = (t_) * 64;                     \
    _Pragma("unroll")                                                 \
    for (int j = 0; j < 4; ++j) {                                     \
      gl_lds16(pA[j] + k0_, &As[b_][sdst[j]]);                        \
      gl_lds16(pB[j] + k0_, &Bs[b_][sdst[j]]);                        \
    }                                                                 \
  } while (0)

  STAGE64(0, 0);
  for (int t = 0; t < NT; ++t) {
    int b = t & 1;
    __syncthreads();                           // implicit vmcnt(0): stage(t) landed
    if (t + 1 < NT) STAGE64(t + 1, b ^ 1);     // issue early -> full 64-k step of slack
    short8 af[4][2], bfr[4][2];
    #pragma unroll
    for (int mi = 0; mi < 4; ++mi)
      #pragma unroll
      for (int ks = 0; ks < 2; ++ks)
        af[mi][ks] = *(const short8*)&As[b][aoffs[ks] + mi * 1024];   // 16 rows = 1024 ush
    #pragma unroll
    for (int ni = 0; ni < 4; ++ni)
      #pragma unroll
      for (int ks = 0; ks < 2; ++ks)
        bfr[ni][ks] = *(const short8*)&Bs[b][boffs[ks] + ni * 1024];
    #pragma unroll
    for (int mi = 0; mi < 4; ++mi)
      #pragma unroll
      for (int ni = 0; ni < 4; ++ni)
        #pragma unroll
        for (int ks = 0; ks < 2; ++ks)
          acc[mi][ni] = __builtin_amdgcn_mfma_f32_16x16x32_bf16(af[mi][ks], bfr[ni][ks], acc[mi][ni], 0, 0, 0);
  }
#undef STAGE64

  #pragma unroll
  for (int ni = 0; ni < 4; ++ni) {
    int colg = (int)n0 + wc * 64 + ni * 16 + l15;
    float bs = bias[colg];
    #pragma unroll
    for (int mi = 0; mi < 4; ++mi) {
      #pragma unroll
      for (int r2 = 0; r2 < 4; ++r2) {
        size_t rowg = m0 + wr * 64 + mi * 16 + kg * 4 + r2;   // C/D: row=(l>>4)*4+r, col=l&15
        outp[rowg * ldo + colg] = f2bf(fmaxf(acc[mi][ni][r2] + bs, 0.f));
      }
    }
  }
}

// ------- H1c[r_local] = relu(V1[src] + A1p[arow]) -> bf16  (b1a pre-folded into A1p) -------
__global__ void k_build_h1(const float* __restrict__ V1, const float* __restrict__ A1p,
                           const int* __restrict__ idx, unsigned short* __restrict__ H1c,
                           int rbase) {
  int row = rbase + blockIdx.x;                // global row 0..133119
  int src, arow;
  if (row < 2048) { src = row; arow = row; }   // rows 0..2047 = query
  else {
    int g = row - 2048; arow = g >> 6;
    int s = idx[g];
    src = s < 0 ? 0 : (s > 2047 ? 2047 : s);
  }
  int j = threadIdx.x * 4;
  float4 v = *(const float4*)(V1 + (size_t)src * 1024 + j);
  float4 a = *(const float4*)(A1p + (size_t)arow * 1024 + j);
  ushort4v o;
  o.x = f2bf(fmaxf(v.x + a.x, 0.f));
  o.y = f2bf(fmaxf(v.y + a.y, 0.f));
  o.z = f2bf(fmaxf(v.z + a.z, 0.f));
  o.w = f2bf(fmaxf(v.w + a.w, 0.f));
  *(ushort4v*)(H1c + (size_t)blockIdx.x * 1024 + j) = o;
}

// ---------------- logits[b,k] = dot(P[b], P[2048 + b*64 + k]) / T  (P is bf16) ----------------
__global__ void k_dot(const unsigned short* __restrict__ P, float* __restrict__ out) {
  __shared__ float q[128];
  int b = blockIdx.x, t = threadIdx.x;
  if (t < 128) q[t] = bf2f(P[(size_t)b * 128 + t]);
  __syncthreads();
  int k = t >> 2, part = t & 3;
  const unsigned short* row = P + (size_t)(2048 + b * 64 + k) * 128 + part * 32;
  const float* qp = q + part * 32;
  float s = 0.f;
  #pragma unroll
  for (int j = 0; j < 32; j += 8) {
    short8 pv = *(const short8*)(row + j);
    #pragma unroll
    for (int e = 0; e < 8; ++e)
      s += bf2f((unsigned short)pv[e]) * qp[j + e];
  }
  s += __shfl_xor(s, 1);
  s += __shfl_xor(s, 2);
  if (part == 0) out[(size_t)b * 64 + k] = s * (float)(1.0 / 0.12);
}

extern "C" void kernel_launch(void* const* d_in, const int* in_sizes, int n_in,
                              void* d_out, int out_size, void* d_ws, size_t ws_size,
                              hipStream_t stream) {
  const float* v2s = (const float*)d_in[0];
  const float* tar = (const float*)d_in[1];
  const int*   sidx = (const int*)d_in[2];
  const float* W2a = (const float*)d_in[3];
  const float* b2a = (const float*)d_in[4];
  const float* W2b = (const float*)d_in[5];
  const float* b2b = (const float*)d_in[6];
  const float* W2c = (const float*)d_in[7];
  const float* b2c = (const float*)d_in[8];
  const float* W1a = (const float*)d_in[9];
  const float* b1a = (const float*)d_in[10];
  const float* W1b = (const float*)d_in[11];
  const float* b1b = (const float*)d_in[12];
  const float* W1c = (const float*)d_in[13];
  const float* b1c = (const float*)d_in[14];
  float* out = (float*)d_out;

  char* ws = (char*)d_ws;
  size_t off = 0;
  auto alloc = [&](size_t bytes) -> char* {
    char* p = ws + off; off += (bytes + 255) & ~(size_t)255; return p;
  };
  // persistent
  unsigned short* W1bT = (unsigned short*)alloc(2048ull * 1024 * 2);  // [2048][1024]
  unsigned short* W1cT = (unsigned short*)alloc(128ull * 2048 * 2);   // [128][2048]
  float*          V1   = (float*)alloc(2048ull * 1024 * 4);           // v2s @ W1a
  float*          A1p  = (float*)alloc(2048ull * 1024 * 4);           // att @ W1a + b1a
  unsigned short* Pb   = (unsigned short*)alloc(133120ull * 128 * 2); // bf16 projections
  // overlay
  size_t O = off;
  off = O;
  unsigned short* W1aT = (unsigned short*)alloc(1024ull * 320 * 2);   // [1024][320]  (K-pad)
  unsigned short* v2sb = (unsigned short*)alloc(2048ull * 320 * 2);
  unsigned short* attb = (unsigned short*)alloc(2048ull * 320 * 2);
  unsigned short* W2bT = (unsigned short*)alloc(2048ull * 1024 * 2);
  unsigned short* W2cT = (unsigned short*)alloc(384ull * 2048 * 2);   // [384][2048]  (N-pad)
  unsigned short* h_a  = (unsigned short*)alloc(2048ull * 1024 * 2);
  unsigned short* h2a  = (unsigned short*)alloc(2048ull * 2048 * 2);
  size_t early_end = off;

  // ---- chunk plans: m-tiles (x256 rows) per chunk, sum = 520 (all row counts % 128 == 0)
  static const int plans[4][8] = {{260,260,0,0,0,0,0,0},
                                  {132,132,128,128,0,0,0,0},
                                  {130,130,130,130,0,0,0,0},
                                  {65,65,65,65,65,65,65,65}};
  int sel = -1, maxmt = 0;
  for (int p = 0; p < 4 && sel < 0; ++p) {
    int mx = 0;
    for (int i = 0; i < 8; ++i) if (plans[p][i] > mx) mx = plans[p][i];
    size_t rows = (size_t)mx * 256;
    size_t late = O + ((rows * 1024 * 2 + 255) & ~(size_t)255)
                    + ((rows * 2048 * 2 + 255) & ~(size_t)255);
    size_t need = late > early_end ? late : early_end;
    if (need <= ws_size) { sel = p; maxmt = mx; }
  }
  int fallR = 0;
  if (sel < 0) {   // NCH=16 fallback
    size_t rows = 133120ull / 16;
    size_t late = O + ((rows * 1024 * 2 + 255) & ~(size_t)255)
                    + ((rows * 2048 * 2 + 255) & ~(size_t)255);
    size_t need = late > early_end ? late : early_end;
    if (need <= ws_size) fallR = (int)rows;
  }
  fprintf(stderr, "[kernel_launch] ws_size=%zu sel=%d\n", ws_size, sel);
  if (sel < 0 && !fallR) {
    hipMemsetAsync(d_out, 0, (size_t)out_size * 4, stream);
    return;
  }
  off = O;
  size_t bufrows = (sel >= 0) ? (size_t)maxmt * 256 : (size_t)fallR;
  unsigned short* H1c = (unsigned short*)alloc(bufrows * 1024 * 2);
  unsigned short* H2c = (unsigned short*)alloc(bufrows * 2048 * 2);

  dim3 blk(256);
  // weight prep (tiled coalesced transpose)
  k_transpose_cast_t<<<dim3(16, 32), blk, 0, stream>>>(W2b, W2bT, 2048, 1024, 1024);
  k_transpose_cast_t<<<dim3(32, 6),  blk, 0, stream>>>(W2c, W2cT, 312, 2048, 2048);
  k_transpose_cast_t<<<dim3(5, 16),  blk, 0, stream>>>(W1a, W1aT, 1024, 312, 320);
  k_transpose_cast_t<<<dim3(16, 32), blk, 0, stream>>>(W1b, W1bT, 2048, 1024, 1024);
  k_transpose_cast_t<<<dim3(32, 2),  blk, 0, stream>>>(W1c, W1cT, 128, 2048, 2048);
  k_att_l1<<<8192, blk, 0, stream>>>(tar, W2a, b2a, h_a);
  k_v2s_cast<<<2560, blk, 0, stream>>>(v2s, v2sb);
  // att MLP (bf16, BK=32 kernel)
  k_gemm_bt<true,  true ><<<256, blk, 0, stream>>>(h_a,  W2bT, b2b, 2048, 16, 2048, 1024, h2a,  2048, 1);
  k_gemm_bt<true,  true ><<<48,  blk, 0, stream>>>(h2a,  W2cT, b2c, 312,  3,  320,  2048, attb, 320,  1);
  // layer-1 factored (bf16 in, f32 out)
  k_gemm_bt<false, false><<<128, blk, 0, stream>>>(v2sb, W1aT, nullptr, 0,  8, 1024, 320, V1,  1024, 1);
  k_gemm_bt<false, false><<<128, blk, 0, stream>>>(attb, W1aT, b1a, 1024,  8, 1024, 320, A1p, 1024, 1);
  // chunked: build H1 -> layer2 (BK=64 kernel) -> layer3
  if (sel >= 0) {
    int rbase = 0;
    for (int i = 0; i < 8 && plans[sel][i]; ++i) {
      int R = plans[sel][i] * 256;
      k_build_h1<<<R, blk, 0, stream>>>(V1, A1p, sidx, H1c, rbase);
      k_gemm64<<<(R / 128) * 16, blk, 0, stream>>>(H1c, W1bT, b1b, 16, 1024, H2c, 2048);
      k_gemm_bt<true, true><<<(R / 128), blk, 0, stream>>>(H2c, W1cT, b1c, 128, 1, 128, 2048,
                                                            Pb + (size_t)rbase * 128, 128, 0);
      rbase += R;
    }
  } else {
    for (int c = 0; c < 16; ++c) {
      int rbase = c * fallR;
      k_build_h1<<<fallR, blk, 0, stream>>>(V1, A1p, sidx, H1c, rbase);
      k_gemm64<<<(fallR / 128) * 16, blk, 0, stream>>>(H1c, W1bT, b1b, 16, 1024, H2c, 2048);
      k_gemm_bt<true, true><<<(fallR / 128), blk, 0, stream>>>(H2c, W1cT, b1c, 128, 1, 128, 2048,
                                                                Pb + (size_t)rbase * 128, 128, 0);
    }
  }
  // logits
  k_dot<<<2048, blk, 0, stream>>>(Pb, out);
}

// Round 13
// 1047.919 us; speedup vs baseline: 4.2201x; 1.0177x over previous
//
#include <hip/hip_runtime.h>
#include <stdio.h>
#include <stdint.h>

typedef __attribute__((ext_vector_type(8))) short short8;     // 8 x bf16 bits (4 VGPRs)
typedef __attribute__((ext_vector_type(4))) float f32x4;      // MFMA accum
typedef __attribute__((ext_vector_type(4))) unsigned short ushort4v;

__device__ __forceinline__ unsigned short f2bf(float f) {
  unsigned int u = __builtin_bit_cast(unsigned int, f);
  u = u + 0x7FFFu + ((u >> 16) & 1u);   // RNE
  return (unsigned short)(u >> 16);
}
__device__ __forceinline__ float bf2f(unsigned short h) {
  unsigned int u = ((unsigned int)h) << 16;
  return __builtin_bit_cast(float, u);
}

// async global->LDS, 16B per lane; LDS dest = wave-uniform base + lane*16
__device__ __forceinline__ void gl_lds16(const void* g, void* l) {
  __builtin_amdgcn_global_load_lds(
      (const __attribute__((address_space(1))) unsigned int*)g,
      (__attribute__((address_space(3))) unsigned int*)l, 16, 0, 0);
}

#define RAW_BAR()  __builtin_amdgcn_s_barrier()
#define LGKM0()    asm volatile("s_waitcnt lgkmcnt(0)" ::: "memory")
#define VMCNT(n_)  asm volatile("s_waitcnt vmcnt(" #n_ ")" ::: "memory")
#define SCHED_FENCE() __builtin_amdgcn_sched_barrier(0)   // rule #18: pin MFMA vs inline-asm waits

// -------- tiled transpose+cast bf16 (+zero pad): out[n][k] = f2bf(in[k][n]) --------
__global__ void k_transpose_cast_t(const float* __restrict__ in, unsigned short* __restrict__ out,
                                   int Nin, int Kin, int ldo) {
  __shared__ float lds[64][65];
  int k0 = blockIdx.x * 64, n0 = blockIdx.y * 64;
  int t = threadIdx.x, tc = t & 15, tr = t >> 4;
  #pragma unroll
  for (int rr = 0; rr < 4; ++rr) {
    int kl = tr + rr * 16, k = k0 + kl;
    #pragma unroll
    for (int j = 0; j < 4; ++j) {
      int nl = tc * 4 + j, n = n0 + nl;
      lds[kl][nl] = (k < Kin && n < Nin) ? in[(size_t)k * Nin + n] : 0.f;
    }
  }
  __syncthreads();
  #pragma unroll
  for (int rr = 0; rr < 4; ++rr) {
    int nl = tr + rr * 16, n = n0 + nl;
    int kb = k0 + tc * 4;
    if (kb + 3 < ldo) {
      ushort4v o;
      o.x = f2bf(lds[tc * 4 + 0][nl]);
      o.y = f2bf(lds[tc * 4 + 1][nl]);
      o.z = f2bf(lds[tc * 4 + 2][nl]);
      o.w = f2bf(lds[tc * 4 + 3][nl]);
      *(ushort4v*)&out[(size_t)n * ldo + kb] = o;
    } else {
      for (int j = 0; j < 4; ++j)
        if (kb + j < ldo) out[(size_t)n * ldo + kb + j] = f2bf(lds[tc * 4 + j][nl]);
    }
  }
}

// ---------------- att layer 1: h = relu(t[b]*W2a[j] + b2a[j]) -> bf16 [2048x1024] ----------------
__global__ void k_att_l1(const float* __restrict__ tar, const float* __restrict__ W2a,
                         const float* __restrict__ b2a, unsigned short* __restrict__ out) {
  int id = blockIdx.x * 256 + threadIdx.x;   // 2048*1024
  int b = id >> 10, j = id & 1023;
  out[id] = f2bf(fmaxf(tar[b] * W2a[j] + b2a[j], 0.f));
}

// ---------------- v2s cast to bf16, K padded 312->320 ----------------
__global__ void k_v2s_cast(const float* __restrict__ v2s, unsigned short* __restrict__ out) {
  int id = blockIdx.x * 256 + threadIdx.x;   // 2048*320
  int r = id / 320, c = id - r * 320;
  out[id] = (c < 312) ? f2bf(v2s[(size_t)r * 312 + c]) : (unsigned short)0;
}

// LDS slot helper (BK=32 kernels)
__device__ __forceinline__ int lds_off(int row, int g) {
  int slot = (g + (row >> 1)) & 3;
  return row * 32 + slot * 8;                 // ushort units, row = 64B
}

// ====== 128x128 bf16 GEMM, BK=32 double-buffered (R8-proven) — att-MLP / layer-1 / layer-3 ======
template<bool RELU, bool OUTBF16>
__global__ __launch_bounds__(256)
void k_gemm_bt(const unsigned short* __restrict__ A, const unsigned short* __restrict__ B,
               const float* __restrict__ bias, int bias_n, int nNt, int N_store, int K,
               void* __restrict__ outp, int ldo, int remap) {
  __shared__ __align__(16) unsigned short As[2][4096];
  __shared__ __align__(16) unsigned short Bs[2][4096];
  int d = blockIdx.x, nwg = gridDim.x;
  int L = d;
  if (remap) { int q = nwg >> 3; L = (d & 7) * q + (d >> 3); }
  int mt = L / nNt, nt = L - mt * nNt;
  size_t m0 = (size_t)mt * 128, n0 = (size_t)nt * 128;
  int tid = threadIdx.x, lane = tid & 63;
  int w = tid >> 6, wr = w >> 1, wc = w & 1;
  int sr = tid >> 2;
  int gch = ((tid & 3) - (tid >> 3)) & 3;
  const unsigned short* pA0 = A + (m0 + sr) * K + gch * 8;
  const unsigned short* pA1 = pA0 + (size_t)64 * K;
  const unsigned short* pB0 = B + (n0 + sr) * K + gch * 8;
  const unsigned short* pB1 = pB0 + (size_t)64 * K;
  int sd = (tid & ~63) * 8;

  int kg = lane >> 4, l15 = lane & 15;
  int aoff = lds_off(wr * 64 + l15, kg);
  int boff = lds_off(wc * 64 + l15, kg);

  f32x4 acc[4][4];
  #pragma unroll
  for (int i = 0; i < 4; ++i)
    #pragma unroll
    for (int j = 0; j < 4; ++j) acc[i][j] = (f32x4)(0.f);

  const int NT = K >> 5;
#define STAGE(t_, b_) do { int k0_ = (t_) * 32;                       \
    gl_lds16(pA0 + k0_, &As[b_][sd]);                                 \
    gl_lds16(pA1 + k0_, &As[b_][2048 + sd]);                          \
    gl_lds16(pB0 + k0_, &Bs[b_][sd]);                                 \
    gl_lds16(pB1 + k0_, &Bs[b_][2048 + sd]);                          \
  } while (0)

  STAGE(0, 0);
  for (int t = 0; t < NT; ++t) {
    int b = t & 1;
    __syncthreads();                          // implicit vmcnt(0): stage(t) landed
    if (t + 1 < NT) STAGE(t + 1, b ^ 1);      // issue early -> full tile of slack
    short8 af[4], bfr[4];
    #pragma unroll
    for (int mi = 0; mi < 4; ++mi) af[mi] = *(const short8*)&As[b][aoff + mi * 512];
    #pragma unroll
    for (int ni = 0; ni < 4; ++ni) bfr[ni] = *(const short8*)&Bs[b][boff + ni * 512];
    #pragma unroll
    for (int mi = 0; mi < 4; ++mi)
      #pragma unroll
      for (int ni = 0; ni < 4; ++ni)
        acc[mi][ni] = __builtin_amdgcn_mfma_f32_16x16x32_bf16(af[mi], bfr[ni], acc[mi][ni], 0, 0, 0);
  }
#undef STAGE

  #pragma unroll
  for (int ni = 0; ni < 4; ++ni) {
    int colg = (int)n0 + wc * 64 + ni * 16 + l15;
    if (colg < N_store) {
      float bs = bias ? (colg < bias_n ? bias[colg] : 0.f) : 0.f;
      #pragma unroll
      for (int mi = 0; mi < 4; ++mi) {
        #pragma unroll
        for (int r2 = 0; r2 < 4; ++r2) {
          size_t rowg = m0 + wr * 64 + mi * 16 + kg * 4 + r2;
          float v = acc[mi][ni][r2] + bs;
          if (RELU) v = fmaxf(v, 0.f);
          if (OUTBF16) ((unsigned short*)outp)[rowg * ldo + colg] = f2bf(v);
          else         ((float*)outp)[rowg * ldo + colg] = v;
        }
      }
    }
  }
}

// ======== 256x256 8-phase GEMM (T3+T4+T5) + sched_barrier(0) pinning (rule #18) ========
// Schedule/liveness identical to R6 (verified correct, absmax 4.88e-4). NEW: SCHED_FENCE()
// after each barrier-wait and around each MFMA cluster so hipcc cannot hoist register-only
// MFMAs across the inline-asm waits (the documented m214 r263/r282 failure mode) — this is
// the hypothesized reason R6 measured identical to the 2-phase kernel.
__global__ __launch_bounds__(512, 2)
void k_gemm256p8(const unsigned short* __restrict__ A, const unsigned short* __restrict__ B,
                 const float* __restrict__ bias, int nNt, int K,
                 unsigned short* __restrict__ outp, int ldo) {
  __shared__ __align__(16) unsigned short sm[65536];   // 128 KiB
  int d0 = blockIdx.x, nwg = gridDim.x;
  int q = nwg >> 3;                            // nwg % 8 == 0 guaranteed by launcher
  int L = (d0 & 7) * q + (d0 >> 3);            // XCD-contiguous chunks
  int mt = L / nNt, nt = L - mt * nNt;
  size_t m0 = (size_t)mt * 256, n0 = (size_t)nt * 256;
  int tid = threadIdx.x, lane = tid & 63;
  int w = tid >> 6, wr = w >> 2, wc = w & 3;

  int srow = tid >> 3;
  int gch = ((tid & 7) - srow) & 7;            // inverse swizzle on global src (rule #21)
  const unsigned short* Asrc = A + (m0 + srow) * K + gch * 8;
  const unsigned short* Bsrc = B + (n0 + srow) * K + gch * 8;
  int sdst = w * 512;                          // wave-uniform; HW adds lane*16B

#define STAGE_A(u_, h_) do { int db_ = ((u_) & 1) * 32768, ko_ = (u_) * 64;          \
    gl_lds16(Asrc + ((h_) * 128 + 0 ) * K + ko_, sm + db_ + (h_) * 8192 + 0    + sdst); \
    gl_lds16(Asrc + ((h_) * 128 + 64) * K + ko_, sm + db_ + (h_) * 8192 + 4096 + sdst); \
  } while (0)
#define STAGE_B(u_, h_) do { int db_ = ((u_) & 1) * 32768 + 16384, ko_ = (u_) * 64;  \
    gl_lds16(Bsrc + ((h_) * 128 + 0 ) * K + ko_, sm + db_ + (h_) * 8192 + 0    + sdst); \
    gl_lds16(Bsrc + ((h_) * 128 + 64) * K + ko_, sm + db_ + (h_) * 8192 + 4096 + sdst); \
  } while (0)

  int kg = lane >> 4, l15 = lane & 15;
  int CA = wr * 128 + l15;
  int CB = wc * 64 + l15;
  int aoffs[2] = { CA * 64 + ((kg + CA) & 7) * 8, CA * 64 + ((kg + CA + 4) & 7) * 8 };
  int boffs[2] = { CB * 64 + ((kg + CB) & 7) * 8, CB * 64 + ((kg + CB + 4) & 7) * 8 };

  f32x4 acc[8][4];
  #pragma unroll
  for (int i = 0; i < 8; ++i)
    #pragma unroll
    for (int j = 0; j < 4; ++j) acc[i][j] = (f32x4)(0.f);

  const int NT = K >> 6;

  STAGE_A(0, 0); STAGE_A(0, 1); STAGE_B(0, 0); STAGE_B(0, 1);
  STAGE_B(1, 0); STAGE_B(1, 1);
  VMCNT(4);
  RAW_BAR();
  SCHED_FENCE();

  short8 af[4][2], bfv[4][2];
  for (int u = 0; u < NT; ++u) {
    const unsigned short* Ab = sm + (u & 1) * 32768;
    const unsigned short* Bb = Ab + 16384;
    // ---- P0: read A(mi0-3)+B(ni0-1); stage A-half0(u+1); MFMA mi0-3 x ni0-1
    #pragma unroll
    for (int mi = 0; mi < 4; ++mi)
      #pragma unroll
      for (int ks = 0; ks < 2; ++ks) af[mi][ks] = *(const short8*)&Ab[aoffs[ks] + mi * 1024];
    #pragma unroll
    for (int ni = 0; ni < 2; ++ni)
      #pragma unroll
      for (int ks = 0; ks < 2; ++ks) bfv[ni][ks] = *(const short8*)&Bb[boffs[ks] + ni * 1024];
    if (u + 1 < NT) STAGE_A(u + 1, 0);
    RAW_BAR(); LGKM0(); SCHED_FENCE();
    __builtin_amdgcn_s_setprio(1);
    #pragma unroll
    for (int mi = 0; mi < 4; ++mi)
      #pragma unroll
      for (int ni = 0; ni < 2; ++ni)
        #pragma unroll
        for (int ks = 0; ks < 2; ++ks)
          acc[mi][ni] = __builtin_amdgcn_mfma_f32_16x16x32_bf16(af[mi][ks], bfv[ni][ks], acc[mi][ni], 0, 0, 0);
    __builtin_amdgcn_s_setprio(0);
    SCHED_FENCE();
    RAW_BAR();
    // ---- P1: read B(ni2-3); stage A-half1(u+1); MFMA mi0-3 x ni2-3
    #pragma unroll
    for (int ni = 2; ni < 4; ++ni)
      #pragma unroll
      for (int ks = 0; ks < 2; ++ks) bfv[ni][ks] = *(const short8*)&Bb[boffs[ks] + ni * 1024];
    if (u + 1 < NT) STAGE_A(u + 1, 1);
    RAW_BAR(); LGKM0(); SCHED_FENCE();
    __builtin_amdgcn_s_setprio(1);
    #pragma unroll
    for (int mi = 0; mi < 4; ++mi)
      #pragma unroll
      for (int ni = 2; ni < 4; ++ni)
        #pragma unroll
        for (int ks = 0; ks < 2; ++ks)
          acc[mi][ni] = __builtin_amdgcn_mfma_f32_16x16x32_bf16(af[mi][ks], bfv[ni][ks], acc[mi][ni], 0, 0, 0);
    __builtin_amdgcn_s_setprio(0);
    SCHED_FENCE();
    RAW_BAR();
    // ---- P2: read A(mi4-7); stage B-half0(u+2); MFMA mi4-7 x ni0-1
    #pragma unroll
    for (int mi = 0; mi < 4; ++mi)
      #pragma unroll
      for (int ks = 0; ks < 2; ++ks) af[mi][ks] = *(const short8*)&Ab[aoffs[ks] + (mi + 4) * 1024];
    if (u + 2 < NT) STAGE_B(u + 2, 0);
    RAW_BAR(); LGKM0(); SCHED_FENCE();
    __builtin_amdgcn_s_setprio(1);
    #pragma unroll
    for (int mi = 0; mi < 4; ++mi)
      #pragma unroll
      for (int ni = 0; ni < 2; ++ni)
        #pragma unroll
        for (int ks = 0; ks < 2; ++ks)
          acc[mi + 4][ni] = __builtin_amdgcn_mfma_f32_16x16x32_bf16(af[mi][ks], bfv[ni][ks], acc[mi + 4][ni], 0, 0, 0);
    __builtin_amdgcn_s_setprio(0);
    SCHED_FENCE();
    RAW_BAR();
    // ---- P3: stage B-half1(u+2); MFMA mi4-7 x ni2-3; counted drain
    if (u + 2 < NT) STAGE_B(u + 2, 1);
    SCHED_FENCE();
    __builtin_amdgcn_s_setprio(1);
    #pragma unroll
    for (int mi = 0; mi < 4; ++mi)
      #pragma unroll
      for (int ni = 2; ni < 4; ++ni)
        #pragma unroll
        for (int ks = 0; ks < 2; ++ks)
          acc[mi + 4][ni] = __builtin_amdgcn_mfma_f32_16x16x32_bf16(af[mi][ks], bfv[ni][ks], acc[mi + 4][ni], 0, 0, 0);
    __builtin_amdgcn_s_setprio(0);
    SCHED_FENCE();
    if (u + 1 < NT) {
      if (u + 2 < NT) { VMCNT(4); }            // tile u+1 landed; B(u+2) stays in flight
      else            { VMCNT(0); }            // last prefetch boundary: drain
      RAW_BAR();
      SCHED_FENCE();
    }
  }
#undef STAGE_A
#undef STAGE_B

  #pragma unroll
  for (int ni = 0; ni < 4; ++ni) {
    int colg = (int)n0 + wc * 64 + ni * 16 + l15;
    float bs = bias[colg];
    #pragma unroll
    for (int mi = 0; mi < 8; ++mi) {
      #pragma unroll
      for (int r2 = 0; r2 < 4; ++r2) {
        size_t rowg = m0 + wr * 128 + mi * 16 + kg * 4 + r2;   // C/D: row=(l>>4)*4+r, col=l&15
        outp[rowg * ldo + colg] = f2bf(fmaxf(acc[mi][ni][r2] + bs, 0.f));
      }
    }
  }
}

// ------- H1c[r_local] = relu(V1[src] + A1p[arow]) -> bf16  (b1a pre-folded into A1p) -------
__global__ void k_build_h1(const float* __restrict__ V1, const float* __restrict__ A1p,
                           const int* __restrict__ idx, unsigned short* __restrict__ H1c,
                           int rbase) {
  int row = rbase + blockIdx.x;                // global row 0..133119
  int src, arow;
  if (row < 2048) { src = row; arow = row; }   // rows 0..2047 = query
  else {
    int g = row - 2048; arow = g >> 6;
    int s = idx[g];
    src = s < 0 ? 0 : (s > 2047 ? 2047 : s);
  }
  int j = threadIdx.x * 4;
  float4 v = *(const float4*)(V1 + (size_t)src * 1024 + j);
  float4 a = *(const float4*)(A1p + (size_t)arow * 1024 + j);
  ushort4v o;
  o.x = f2bf(fmaxf(v.x + a.x, 0.f));
  o.y = f2bf(fmaxf(v.y + a.y, 0.f));
  o.z = f2bf(fmaxf(v.z + a.z, 0.f));
  o.w = f2bf(fmaxf(v.w + a.w, 0.f));
  *(ushort4v*)(H1c + (size_t)blockIdx.x * 1024 + j) = o;
}

// ---------------- logits[b,k] = dot(P[b], P[2048 + b*64 + k]) / T  (P is bf16) ----------------
__global__ void k_dot(const unsigned short* __restrict__ P, float* __restrict__ out) {
  __shared__ float q[128];
  int b = blockIdx.x, t = threadIdx.x;
  if (t < 128) q[t] = bf2f(P[(size_t)b * 128 + t]);
  __syncthreads();
  int k = t >> 2, part = t & 3;
  const unsigned short* row = P + (size_t)(2048 + b * 64 + k) * 128 + part * 32;
  const float* qp = q + part * 32;
  float s = 0.f;
  #pragma unroll
  for (int j = 0; j < 32; j += 8) {
    short8 pv = *(const short8*)(row + j);
    #pragma unroll
    for (int e = 0; e < 8; ++e)
      s += bf2f((unsigned short)pv[e]) * qp[j + e];
  }
  s += __shfl_xor(s, 1);
  s += __shfl_xor(s, 2);
  if (part == 0) out[(size_t)b * 64 + k] = s * (float)(1.0 / 0.12);
}

extern "C" void kernel_launch(void* const* d_in, const int* in_sizes, int n_in,
                              void* d_out, int out_size, void* d_ws, size_t ws_size,
                              hipStream_t stream) {
  const float* v2s = (const float*)d_in[0];
  const float* tar = (const float*)d_in[1];
  const int*   sidx = (const int*)d_in[2];
  const float* W2a = (const float*)d_in[3];
  const float* b2a = (const float*)d_in[4];
  const float* W2b = (const float*)d_in[5];
  const float* b2b = (const float*)d_in[6];
  const float* W2c = (const float*)d_in[7];
  const float* b2c = (const float*)d_in[8];
  const float* W1a = (const float*)d_in[9];
  const float* b1a = (const float*)d_in[10];
  const float* W1b = (const float*)d_in[11];
  const float* b1b = (const float*)d_in[12];
  const float* W1c = (const float*)d_in[13];
  const float* b1c = (const float*)d_in[14];
  float* out = (float*)d_out;

  char* ws = (char*)d_ws;
  size_t off = 0;
  auto alloc = [&](size_t bytes) -> char* {
    char* p = ws + off; off += (bytes + 255) & ~(size_t)255; return p;
  };
  // persistent
  unsigned short* W1bT = (unsigned short*)alloc(2048ull * 1024 * 2);  // [2048][1024]
  unsigned short* W1cT = (unsigned short*)alloc(128ull * 2048 * 2);   // [128][2048]
  float*          V1   = (float*)alloc(2048ull * 1024 * 4);           // v2s @ W1a
  float*          A1p  = (float*)alloc(2048ull * 1024 * 4);           // att @ W1a + b1a
  unsigned short* Pb   = (unsigned short*)alloc(133120ull * 128 * 2); // bf16 projections
  // overlay
  size_t O = off;
  off = O;
  unsigned short* W1aT = (unsigned short*)alloc(1024ull * 320 * 2);   // [1024][320]  (K-pad)
  unsigned short* v2sb = (unsigned short*)alloc(2048ull * 320 * 2);
  unsigned short* attb = (unsigned short*)alloc(2048ull * 320 * 2);
  unsigned short* W2bT = (unsigned short*)alloc(2048ull * 1024 * 2);
  unsigned short* W2cT = (unsigned short*)alloc(384ull * 2048 * 2);   // [384][2048]  (N-pad)
  unsigned short* h_a  = (unsigned short*)alloc(2048ull * 1024 * 2);
  unsigned short* h2a  = (unsigned short*)alloc(2048ull * 2048 * 2);
  size_t early_end = off;

  // ---- chunk plans: m-tiles (x256 rows) per chunk, sum = 520 (all row counts % 256 == 0)
  static const int plans[4][8] = {{260,260,0,0,0,0,0,0},
                                  {132,132,128,128,0,0,0,0},
                                  {130,130,130,130,0,0,0,0},
                                  {65,65,65,65,65,65,65,65}};
  int sel = -1, maxmt = 0;
  for (int p = 0; p < 4 && sel < 0; ++p) {
    int mx = 0;
    for (int i = 0; i < 8; ++i) if (plans[p][i] > mx) mx = plans[p][i];
    size_t rows = (size_t)mx * 256;
    size_t late = O + ((rows * 1024 * 2 + 255) & ~(size_t)255)
                    + ((rows * 2048 * 2 + 255) & ~(size_t)255);
    size_t need = late > early_end ? late : early_end;
    if (need <= ws_size) { sel = p; maxmt = mx; }
  }
  int fallR = 0;
  if (sel < 0) {   // NCH=16 fallback
    size_t rows = 133120ull / 16;
    size_t late = O + ((rows * 1024 * 2 + 255) & ~(size_t)255)
                    + ((rows * 2048 * 2 + 255) & ~(size_t)255);
    size_t need = late > early_end ? late : early_end;
    if (need <= ws_size) fallR = (int)rows;
  }
  fprintf(stderr, "[kernel_launch] ws_size=%zu sel=%d\n", ws_size, sel);
  if (sel < 0 && !fallR) {
    hipMemsetAsync(d_out, 0, (size_t)out_size * 4, stream);
    return;
  }
  off = O;
  size_t bufrows = (sel >= 0) ? (size_t)maxmt * 256 : (size_t)fallR;
  unsigned short* H1c = (unsigned short*)alloc(bufrows * 1024 * 2);
  unsigned short* H2c = (unsigned short*)alloc(bufrows * 2048 * 2);

  dim3 blk(256);
  // weight prep (tiled coalesced transpose)
  k_transpose_cast_t<<<dim3(16, 32), blk, 0, stream>>>(W2b, W2bT, 2048, 1024, 1024);
  k_transpose_cast_t<<<dim3(32, 6),  blk, 0, stream>>>(W2c, W2cT, 312, 2048, 2048);
  k_transpose_cast_t<<<dim3(5, 16),  blk, 0, stream>>>(W1a, W1aT, 1024, 312, 320);
  k_transpose_cast_t<<<dim3(16, 32), blk, 0, stream>>>(W1b, W1bT, 2048, 1024, 1024);
  k_transpose_cast_t<<<dim3(32, 2),  blk, 0, stream>>>(W1c, W1cT, 128, 2048, 2048);
  k_att_l1<<<8192, blk, 0, stream>>>(tar, W2a, b2a, h_a);
  k_v2s_cast<<<2560, blk, 0, stream>>>(v2s, v2sb);
  // att MLP (bf16, BK=32 kernel)
  k_gemm_bt<true,  true ><<<256, blk, 0, stream>>>(h_a,  W2bT, b2b, 2048, 16, 2048, 1024, h2a,  2048, 1);
  k_gemm_bt<true,  true ><<<48,  blk, 0, stream>>>(h2a,  W2cT, b2c, 312,  3,  320,  2048, attb, 320,  1);
  // layer-1 factored (bf16 in, f32 out)
  k_gemm_bt<false, false><<<128, blk, 0, stream>>>(v2sb, W1aT, nullptr, 0,  8, 1024, 320, V1,  1024, 1);
  k_gemm_bt<false, false><<<128, blk, 0, stream>>>(attb, W1aT, b1a, 1024,  8, 1024, 320, A1p, 1024, 1);
  // chunked: build H1 -> layer2 (8-phase 256², sched-fenced) -> layer3
  if (sel >= 0) {
    int rbase = 0;
    for (int i = 0; i < 8 && plans[sel][i]; ++i) {
      int mtc = plans[sel][i];
      int R = mtc * 256;
      k_build_h1<<<R, blk, 0, stream>>>(V1, A1p, sidx, H1c, rbase);
      k_gemm256p8<<<mtc * 8, dim3(512), 0, stream>>>(H1c, W1bT, b1b, 8, 1024, H2c, 2048);
      k_gemm_bt<true, true><<<(R / 128), blk, 0, stream>>>(H2c, W1cT, b1c, 128, 1, 128, 2048,
                                                            Pb + (size_t)rbase * 128, 128, 0);
      rbase += R;
    }
  } else {
    for (int c = 0; c < 16; ++c) {
      int rbase = c * fallR;
      k_build_h1<<<fallR, blk, 0, stream>>>(V1, A1p, sidx, H1c, rbase);
      k_gemm_bt<true, true><<<(fallR / 128) * 16, blk, 0, stream>>>(H1c, W1bT, b1b, 2048, 16, 2048, 1024, H2c, 2048, 1);
      k_gemm_bt<true, true><<<(fallR / 128), blk, 0, stream>>>(H2c, W1cT, b1c, 128, 1, 128, 2048,
                                                                Pb + (size_t)rbase * 128, 128, 0);
    }
  }
  // logits
  k_dot<<<2048, blk, 0, stream>>>(Pb, out);
}